// Round 4
// baseline (4055.772 us; speedup 1.0000x reference)
//
#include <hip/hip_runtime.h>

#define NPOS 65536
#define NSTEPS 12

// ---------------- workspace layout (bytes) ----------------
#define USTATE_OFF  0ull                      // 2*65536*128*4 = 67108864
#define STATS_OFF   67108864ull               // float[32]
#define H_OFF       (STATS_OFF + 128ull)      // float[2][256]
#define POOLED0_OFF (H_OFF + 2048ull)         // float[256]
#define PARTS_OFF   (POOLED0_OFF + 1024ull)   // float[3][32][256]
#define WS_END      (PARTS_OFF + 98304ull)
#define ZERO_BYTES  (WS_END - STATS_OFF)

// ---------------- LDS layout (float offsets) ----------------
#define L_W    0        // 16384 floats = 64KB (one W half)
#define L_Y1   16384    // 64 rows * 257 = 16448 floats
#define L_X    32832    // 64 * 64 = 4096 floats
#define L_POOL 36928    // 256
#define L_AH   37184    // 256
#define L_RED  37440    // 512*4 = 2048
#define L_SCR  39488    // 16
#define L_TOT  39504    // * 4B = 158016 bytes
#define SMEM_BYTES (L_TOT * 4)

__device__ __forceinline__ float gelu_erf(float x) {
  return 0.5f * x * (1.0f + erff(x * 0.70710678118654752440f));
}

// ---------------- initial pooled sums + sum|u0| ----------------
__global__ __launch_bounds__(256) void pool0_kernel(const float* __restrict__ u,
                                                    float* __restrict__ pooled0,
                                                    float* __restrict__ stats) {
  int bc = blockIdx.x;  // b*128 + c
  const float4* src = (const float4*)(u + (size_t)bc * NPOS);
  int t = threadIdx.x;
  float s = 0.f, sa = 0.f;
#pragma unroll 4
  for (int i = 0; i < 64; ++i) {
    float4 v = src[i * 256 + t];
    s += v.x + v.y + v.z + v.w;
    sa += fabsf(v.x) + fabsf(v.y) + fabsf(v.z) + fabsf(v.w);
  }
  for (int o = 1; o < 64; o <<= 1) { s += __shfl_xor(s, o, 64); sa += __shfl_xor(sa, o, 64); }
  __shared__ float sc[8];
  int lane = t & 63, w = t >> 6;
  if (lane == 0) { sc[w] = s; sc[4 + w] = sa; }
  __syncthreads();
  if (t == 0) {
    pooled0[bc] = sc[0] + sc[1] + sc[2] + sc[3];
    atomicAdd(&stats[0], sc[4] + sc[5] + sc[6] + sc[7]);
  }
}

// ---------------- fused step, pure fp32 VALU react ----------------
// MODE 0: read d_in u (B,C,THW); MODE 1: in-place ustate (pos,C); MODE 2: write d_out (B,C,THW)
template <int MODE>
__global__ __launch_bounds__(512)
void fused_step(const float* __restrict__ u_in, float* __restrict__ ustate,
                float* __restrict__ d_out,
                const float* __restrict__ gamma, const float* __restrict__ beta,
                const float* __restrict__ W1, const float* __restrict__ b1,
                const float* __restrict__ W2,
                const float* __restrict__ Wg, const float* __restrict__ bg,
                const float* __restrict__ Wv, const float* __restrict__ bv,
                const float* __restrict__ b2,
                const float* __restrict__ alpha_p, const float* __restrict__ logdt_p,
                float* __restrict__ h_g, const float* __restrict__ pooled0,
                float* __restrict__ parts, float* __restrict__ stats, int step) {
  extern __shared__ float sm[];
  float* sW   = sm + L_W;
  float* sY   = sm + L_Y1;
  float* sX   = sm + L_X;
  float* sPool = sm + L_POOL;
  float* sAh  = sm + L_AH;
  float* sRed = sm + L_RED;
  float* sScr = sm + L_SCR;

  int t = threadIdx.x;
  int bid = blockIdx.x;

  // zero the parts slot that step+1 accumulates into
  {
    int zb = (step + 2) % 3;
    for (int i = t; i < 8192; i += 512) parts[zb * 8192 + i] = 0.f;
  }
  // pooled means of current state
  if (t < 256) {
    float ps;
    if (MODE == 0) {
      ps = pooled0[t];
    } else {
      const float* pp = parts + (size_t)(step % 3) * 8192;
      ps = 0.f;
#pragma unroll
      for (int s = 0; s < 32; ++s) ps += pp[s * 256 + t];
    }
    sPool[t] = ps * (1.0f / 65536.0f);
  }
  __syncthreads();
  // memory pump (redundant per block; block 0 commits h)
  if (t < 256) {
    int bb = t >> 7, c = t & 127;
    float gi = bg[c], vi = bv[c];
    const float* pl = sPool + bb * 128;
    for (int k = 0; k < 128; ++k) {
      float pv = pl[k];
      gi = fmaf(pv, Wg[k * 128 + c], gi);
      vi = fmaf(pv, Wv[k * 128 + c], vi);
    }
    float sg = 1.0f / (1.0f + expf(-gi));
    float th = tanhf(vi);
    int hb = step & 1;
    float hn = h_g[hb * 256 + t] + sg * th;
    if (MODE < 2 && bid == 0) h_g[(hb ^ 1) * 256 + t] = hn;
    float aa = log1pf(expf(alpha_p[0]));   // softplus(alpha)
    sAh[t] = aa * hn + b2[c];              // fold b2
  }
  __syncthreads();

  float dtv = fminf(fmaxf(expf(logdt_p[0]), 0.01f), 0.2f);
  int b = bid >> 8;                    // 512 blocks: 0..255 -> b=0, 256..511 -> b=1
  int og = t & 63, pgw = t >> 6;       // GEMM1 mapping: 4 o's, 8 pos
  int og2 = t & 31, pg2 = t >> 5;      // GEMM2 mapping: 4 o2's, 4 pos
  int lane = t & 63, wv = t >> 6;

  float preg[4] = {0.f, 0.f, 0.f, 0.f};
  float acc_ad = 0.f, acc_au = 0.f;

  float4* sWf = (float4*)sW;
  const float4* W1f = (const float4*)W1;
  const float4* W2f = (const float4*)W2;

  for (int tt = 0; tt < 4; ++tt) {
    int pos0 = bid * 256 + tt * 64;
    int n0 = pos0 & (NPOS - 1);

    // ---- GEMM1: y1[o=256][pos] = x @ W1, split over c-halves ----
    float a1[4][8];
#pragma unroll
    for (int i = 0; i < 4; ++i)
#pragma unroll
      for (int k = 0; k < 8; ++k) a1[i][k] = 0.f;

    for (int h = 0; h < 2; ++h) {
      __syncthreads();  // prior users of sW/sX done
      // stage W1 rows [h*64 .. h*64+63] x [256]  (16384 floats)
#pragma unroll
      for (int it = 0; it < 8; ++it) {
        int idx = it * 512 + t;
        sWf[idx] = W1f[(size_t)(h * 64 + (idx >> 6)) * 64 + (idx & 63)];
      }
      // stage x[64 pos][64 c-half]
      if (MODE == 0) {
#pragma unroll
        for (int it = 0; it < 8; ++it) {
          int idx = it * 512 + t;
          int pp_ = idx & 63, cc = idx >> 6;
          sX[pp_ * 64 + cc] =
              u_in[(size_t)(b * 128 + h * 64 + cc) * NPOS + (size_t)(n0 + pp_)];
        }
      } else {
        float4* sXf = (float4*)sX;
        const float4* us4 = (const float4*)ustate;
#pragma unroll
        for (int it = 0; it < 2; ++it) {
          int idx = it * 512 + t;
          int pp_ = idx >> 4, c4 = idx & 15;
          sXf[pp_ * 16 + c4] = us4[(size_t)(pos0 + pp_) * 32 + h * 16 + c4];
        }
      }
      __syncthreads();
      const float4* Wc = (const float4*)sW;
      for (int cc = 0; cc < 64; ++cc) {
        float4 w = Wc[cc * 64 + og];
        float xv[8];
#pragma unroll
        for (int k = 0; k < 8; ++k) xv[k] = sX[(pgw * 8 + k) * 64 + cc];
#pragma unroll
        for (int k = 0; k < 8; ++k) {
          a1[0][k] = fmaf(w.x, xv[k], a1[0][k]);
          a1[1][k] = fmaf(w.y, xv[k], a1[1][k]);
          a1[2][k] = fmaf(w.z, xv[k], a1[2][k]);
          a1[3][k] = fmaf(w.w, xv[k], a1[3][k]);
        }
      }
    }
    // bias + gelu -> y1 LDS (each wave writes its own 8 rows; readers sync later)
    {
      float bb1[4];
#pragma unroll
      for (int i = 0; i < 4; ++i) bb1[i] = b1[og * 4 + i];
#pragma unroll
      for (int k = 0; k < 8; ++k)
#pragma unroll
        for (int i = 0; i < 4; ++i)
          sY[(pgw * 8 + k) * 257 + og * 4 + i] = gelu_erf(a1[i][k] + bb1[i]);
    }

    // ---- GEMM2: react[o2=128][pos] = y1 @ W2, split over k2-halves ----
    float a2[4][4];
#pragma unroll
    for (int i = 0; i < 4; ++i)
#pragma unroll
      for (int k = 0; k < 4; ++k) a2[i][k] = 0.f;

    for (int h = 0; h < 2; ++h) {
      __syncthreads();  // y1 writes visible; prior sW use done
#pragma unroll
      for (int it = 0; it < 8; ++it) {
        int idx = it * 512 + t;
        sWf[idx] = W2f[(size_t)(h * 128 + (idx >> 5)) * 32 + (idx & 31)];
      }
      __syncthreads();
      const float4* Wc = (const float4*)sW;
      for (int cc = 0; cc < 128; ++cc) {
        float4 w = Wc[cc * 32 + og2];
        float yv[4];
#pragma unroll
        for (int k = 0; k < 4; ++k) yv[k] = sY[(pg2 * 4 + k) * 257 + h * 128 + cc];
#pragma unroll
        for (int k = 0; k < 4; ++k) {
          a2[0][k] = fmaf(w.x, yv[k], a2[0][k]);
          a2[1][k] = fmaf(w.y, yv[k], a2[1][k]);
          a2[2][k] = fmaf(w.z, yv[k], a2[2][k]);
          a2[3][k] = fmaf(w.w, yv[k], a2[3][k]);
        }
      }
    }

    // ---- epilogue: du, residual, LN, store, stats, pooled ----
    int ch0 = og2 * 4;
    float ahv[4], gmv[4], btv[4];
#pragma unroll
    for (int i = 0; i < 4; ++i) {
      ahv[i] = sAh[b * 128 + ch0 + i];
      gmv[i] = gamma[ch0 + i];
      btv[i] = beta[ch0 + i];
    }
#pragma unroll
    for (int k = 0; k < 4; ++k) {
      int pos = pos0 + pg2 * 4 + k;
      int n = pos & (NPOS - 1);
      float uf[4];
      if (MODE == 0) {
#pragma unroll
        for (int i = 0; i < 4; ++i)
          uf[i] = u_in[(size_t)(b * 128 + ch0 + i) * NPOS + n];
      } else {
        float4 q = *(const float4*)(ustate + (size_t)pos * 128 + ch0);
        uf[0] = q.x; uf[1] = q.y; uf[2] = q.z; uf[3] = q.w;
      }
      float x[4], s1 = 0.f, s2 = 0.f;
#pragma unroll
      for (int i = 0; i < 4; ++i) {
        float du = a2[i][k] + ahv[i];
        x[i] = uf[i] + dtv * du;
        s1 += x[i]; s2 += x[i] * x[i];
      }
      // LN reduce over the 32 threads (og2) sharing this position (half-wave)
      for (int o = 1; o < 32; o <<= 1) {
        s1 += __shfl_xor(s1, o, 64);
        s2 += __shfl_xor(s2, o, 64);
      }
      float mean = s1 * (1.0f / 128.0f);
      float var = s2 * (1.0f / 128.0f) - mean * mean;
      float rstd = rsqrtf(var + 1e-5f);
      float un[4];
#pragma unroll
      for (int i = 0; i < 4; ++i) un[i] = (x[i] - mean) * rstd * gmv[i] + btv[i];
      if (MODE == 2) {
#pragma unroll
        for (int i = 0; i < 4; ++i)
          d_out[(size_t)(b * 128 + ch0 + i) * NPOS + n] = un[i];
      } else {
        *(float4*)(ustate + (size_t)pos * 128 + ch0) =
            make_float4(un[0], un[1], un[2], un[3]);
      }
#pragma unroll
      for (int i = 0; i < 4; ++i) {
        acc_ad += fabsf(un[i] - uf[i]);
        acc_au += fabsf(un[i]);
        preg[i] += un[i];
      }
    }
  }  // tile loop

  // ---- block reductions: stats + pooled parts (no LDS atomics) ----
  for (int o = 1; o < 64; o <<= 1) {
    acc_ad += __shfl_xor(acc_ad, o, 64);
    acc_au += __shfl_xor(acc_au, o, 64);
  }
  if (lane == 0) { sScr[wv] = acc_ad; sScr[8 + wv] = acc_au; }
#pragma unroll
  for (int i = 0; i < 4; ++i) sRed[t * 4 + i] = preg[i];
  __syncthreads();
  if (t == 0) {
    float ad = 0.f, au = 0.f;
#pragma unroll
    for (int w = 0; w < 8; ++w) { ad += sScr[w]; au += sScr[8 + w]; }
    atomicAdd(&stats[17 + step], ad);  // sum|u_new - u_prev| for this step
    atomicAdd(&stats[1 + step], au);   // sum|u_new|
  }
  if (MODE < 2 && t < 128) {
    float v = 0.f;
#pragma unroll
    for (int pg = 0; pg < 16; ++pg) v += sRed[(pg * 32 + (t >> 2)) * 4 + (t & 3)];
    atomicAdd(&parts[(size_t)((step + 1) % 3) * 8192 + (bid & 31) * 256 + b * 128 + t], v);
  }
}

__global__ void finalize_kernel(const float* __restrict__ stats, float* __restrict__ out) {
  if (threadIdx.x == 0 && blockIdx.x == 0) {
    const float inv = 1.0f / 16777216.0f;  // mean over B*N*C
    float tm = 0.f;
#pragma unroll
    for (int k = 1; k <= 12; ++k)
      tm += (stats[16 + k] * inv) / (stats[k - 1] * inv + 1e-8f);
    out[16777216] = tm * (1.0f / 12.0f);
  }
}

extern "C" void kernel_launch(void* const* d_in, const int* in_sizes, int n_in,
                              void* d_out, int out_size, void* d_ws, size_t ws_size,
                              hipStream_t stream) {
  const float* u     = (const float*)d_in[0];
  const float* Wg    = (const float*)d_in[1];
  const float* bg    = (const float*)d_in[2];
  const float* Wv    = (const float*)d_in[3];
  const float* bv    = (const float*)d_in[4];
  const float* W1    = (const float*)d_in[5];
  const float* b1    = (const float*)d_in[6];
  const float* W2    = (const float*)d_in[7];
  const float* b2    = (const float*)d_in[8];
  const float* gamma = (const float*)d_in[9];
  const float* beta  = (const float*)d_in[10];
  const float* alpha = (const float*)d_in[11];
  const float* logdt = (const float*)d_in[12];
  float* out = (float*)d_out;
  char* ws = (char*)d_ws;
  if (ws_size < WS_END) return;

  float* ustate  = (float*)(ws + USTATE_OFF);
  float* stats   = (float*)(ws + STATS_OFF);
  float* h_g     = (float*)(ws + H_OFF);
  float* pooled0 = (float*)(ws + POOLED0_OFF);
  float* parts   = (float*)(ws + PARTS_OFF);

  hipFuncSetAttribute(reinterpret_cast<const void*>(&fused_step<0>),
                      hipFuncAttributeMaxDynamicSharedMemorySize, SMEM_BYTES);
  hipFuncSetAttribute(reinterpret_cast<const void*>(&fused_step<1>),
                      hipFuncAttributeMaxDynamicSharedMemorySize, SMEM_BYTES);
  hipFuncSetAttribute(reinterpret_cast<const void*>(&fused_step<2>),
                      hipFuncAttributeMaxDynamicSharedMemorySize, SMEM_BYTES);

  hipMemsetAsync(ws + STATS_OFF, 0, ZERO_BYTES, stream);
  pool0_kernel<<<256, 256, 0, stream>>>(u, pooled0, stats);

  for (int step = 0; step < NSTEPS; ++step) {
    if (step == 0)
      fused_step<0><<<512, 512, SMEM_BYTES, stream>>>(
          u, ustate, out, gamma, beta, W1, b1, W2, Wg, bg, Wv, bv, b2,
          alpha, logdt, h_g, pooled0, parts, stats, step);
    else if (step == NSTEPS - 1)
      fused_step<2><<<512, 512, SMEM_BYTES, stream>>>(
          u, ustate, out, gamma, beta, W1, b1, W2, Wg, bg, Wv, bv, b2,
          alpha, logdt, h_g, pooled0, parts, stats, step);
    else
      fused_step<1><<<512, 512, SMEM_BYTES, stream>>>(
          u, ustate, out, gamma, beta, W1, b1, W2, Wg, bg, Wv, bv, b2,
          alpha, logdt, h_g, pooled0, parts, stats, step);
  }
  finalize_kernel<<<1, 64, 0, stream>>>(stats, out);
}